// Round 1
// baseline (230.422 us; speedup 1.0000x reference)
//
#include <hip/hip_runtime.h>

#define BATCH 8
#define DIMC 128
#define NTOT 32768
#define HEADS 4
#define DHEAD 32
#define SCALE_Q 0.17677669529663687f

typedef _Float16 half8  __attribute__((ext_vector_type(8)));
typedef _Float16 half4v __attribute__((ext_vector_type(4)));
typedef _Float16 half2v __attribute__((ext_vector_type(2)));
typedef float    f32x4  __attribute__((ext_vector_type(4)));

// workspace byte offsets (all 16B aligned)
#define WS_WQKV 0        // _Float16[384*128]   = 98304 B
#define WS_WOUT 98304    // _Float16[128*128]   = 32768 B
#define WS_S    131072   // float[8*4*32*32]    = 131072 B
#define WS_Z    262144   // float[8*4*32]       = 4096 B
#define WS_C    266240   // float[8*4*32*32]    = 131072 B
#define WS_ST   397312   // float[16]
#define WS_NEED 397376

// ---------------- K0: convert weights to f16, zero accumulators ----------------
__global__ void k0_prep(const float* __restrict__ wqkv, const float* __restrict__ wout,
                        char* __restrict__ ws) {
    int i = blockIdx.x * 256 + threadIdx.x;
    _Float16* Wb = (_Float16*)(ws + WS_WQKV);
    _Float16* Wo = (_Float16*)(ws + WS_WOUT);
    float* S  = (float*)(ws + WS_S);
    float* Z  = (float*)(ws + WS_Z);
    float* St = (float*)(ws + WS_ST);
    if (i < 49152) Wb[i] = (_Float16)wqkv[i];
    int j = i - 49152;
    if (j >= 0 && j < 16384) Wo[j] = (_Float16)wout[j];
    int k = j - 16384;
    if (k >= 0 && k < 32768) S[k] = 0.f;
    int m = k - 32768;
    if (m >= 0 && m < 1024) Z[m] = 0.f;
    int s = m - 1024;
    if (s >= 0 && s < 16) St[s] = 0.f;
}

// ---------------- K1: k,v projection + S = sum_n exp(k) v^T, Z = sum_n exp(k) ----------------
// grid (64, 8) x 256 thr; each block does 8 n-tiles of 64, S/Z in regs, one atomic flush.
__global__ __launch_bounds__(256, 2) void k1_kv(const float* __restrict__ x,
                                                const _Float16* __restrict__ Wb,
                                                float* __restrict__ S,
                                                float* __restrict__ Z) {
    __shared__ _Float16 Xb[64][136];   // x^T tile: [j][c], pad 8 -> stride 272B
    __shared__ _Float16 KB[128][72];   // exp(k): [h*32+d][j], pad 8 -> stride 144B
    __shared__ _Float16 VB[128][72];   // v:      [h*32+e][j]
    const int t = threadIdx.x;
    const int lane = t & 63, w = t >> 6, g = lane >> 4, l15 = lane & 15;
    const int b = blockIdx.y;

    // preload W A-frags for this wave's 4 m-tiles (rows 128..383), reused all 8 iters
    half8 af[4][4];
#pragma unroll
    for (int mt = 0; mt < 4; ++mt)
#pragma unroll
        for (int kc = 0; kc < 4; ++kc)
            af[mt][kc] = *(const half8*)(Wb + (size_t)(128 + (w * 4 + mt) * 16 + l15) * 128 + kc * 32 + 8 * g);

    f32x4 sacc[2][2];
#pragma unroll
    for (int dm = 0; dm < 2; ++dm)
#pragma unroll
        for (int en = 0; en < 2; ++en) sacc[dm][en] = (f32x4){0.f, 0.f, 0.f, 0.f};
    float zpart = 0.f;

    const int j4 = t & 15, c0 = t >> 4;

    for (int it = 0; it < 8; ++it) {
        const int j0 = (blockIdx.x + 64 * it) * 64;
        __syncthreads();
        // stage x^T tile (f32 -> f16, transpose)
#pragma unroll
        for (int cc = 0; cc < 8; ++cc) {
            const int c = c0 + 16 * cc;
            const float4 v4 = *(const float4*)(x + ((size_t)b * DIMC + c) * NTOT + j0 + 4 * j4);
            Xb[4 * j4 + 0][c] = (_Float16)v4.x;
            Xb[4 * j4 + 1][c] = (_Float16)v4.y;
            Xb[4 * j4 + 2][c] = (_Float16)v4.z;
            Xb[4 * j4 + 3][c] = (_Float16)v4.w;
        }
        __syncthreads();
        // qkv GEMM (rows 128..383): B-frags from Xb
        half8 bf[4][4];
#pragma unroll
        for (int nt = 0; nt < 4; ++nt)
#pragma unroll
            for (int kc = 0; kc < 4; ++kc)
                bf[nt][kc] = *(const half8*)(&Xb[nt * 16 + l15][kc * 32 + 8 * g]);
#pragma unroll
        for (int mt = 0; mt < 4; ++mt) {
            f32x4 a0 = (f32x4){0.f,0.f,0.f,0.f}, a1 = a0, a2 = a0, a3 = a0;
#pragma unroll
            for (int kc = 0; kc < 4; ++kc) {
                a0 = __builtin_amdgcn_mfma_f32_16x16x32_f16(af[mt][kc], bf[0][kc], a0, 0, 0, 0);
                a1 = __builtin_amdgcn_mfma_f32_16x16x32_f16(af[mt][kc], bf[1][kc], a1, 0, 0, 0);
                a2 = __builtin_amdgcn_mfma_f32_16x16x32_f16(af[mt][kc], bf[2][kc], a2, 0, 0, 0);
                a3 = __builtin_amdgcn_mfma_f32_16x16x32_f16(af[mt][kc], bf[3][kc], a3, 0, 0, 0);
            }
            const int lr0 = (w * 4 + mt) * 16 + g * 4;  // 0..255; waves 0,1 -> k, waves 2,3 -> v
#pragma unroll
            for (int nt = 0; nt < 4; ++nt) {
                const f32x4 a = (nt == 0) ? a0 : (nt == 1) ? a1 : (nt == 2) ? a2 : a3;
                const int jn = nt * 16 + l15;
                if (lr0 < 128) {
#pragma unroll
                    for (int r = 0; r < 4; ++r) KB[lr0 + r][jn] = (_Float16)__expf(a[r]);
                } else {
#pragma unroll
                    for (int r = 0; r < 4; ++r) VB[lr0 - 128 + r][jn] = (_Float16)a[r];
                }
            }
        }
        __syncthreads();
        // S partial via MFMA (wave w -> head w), accumulate in regs
#pragma unroll
        for (int dm = 0; dm < 2; ++dm)
#pragma unroll
            for (int en = 0; en < 2; ++en)
#pragma unroll
                for (int kc = 0; kc < 2; ++kc) {
                    half8 ka = *(const half8*)(&KB[w * 32 + dm * 16 + l15][kc * 32 + 8 * g]);
                    half8 vb = *(const half8*)(&VB[w * 32 + en * 16 + l15][kc * 32 + 8 * g]);
                    sacc[dm][en] = __builtin_amdgcn_mfma_f32_16x16x32_f16(ka, vb, sacc[dm][en], 0, 0, 0);
                }
        // Z partial: 2 lanes per d-row
        {
            const _Float16* row = &KB[w * 32 + (lane >> 1)][(lane & 1) * 32];
#pragma unroll
            for (int s8 = 0; s8 < 4; ++s8) {
                half8 hv = *(const half8*)(row + 8 * s8);
#pragma unroll
                for (int e = 0; e < 8; ++e) zpart += (float)hv[e];
            }
        }
    }
    // flush
    {
        float zt = zpart + __shfl_xor(zpart, 1);
        if ((lane & 1) == 0) atomicAdd(&Z[(b * HEADS + w) * DHEAD + (lane >> 1)], zt);
    }
#pragma unroll
    for (int dm = 0; dm < 2; ++dm)
#pragma unroll
        for (int en = 0; en < 2; ++en)
#pragma unroll
            for (int r = 0; r < 4; ++r)
                atomicAdd(&S[((size_t)(b * HEADS + w) * DHEAD + dm * 16 + g * 4 + r) * DHEAD + en * 16 + l15],
                          sacc[dm][en][r]);
}

// ---------------- K2: c = S / Z (row-normalize) ----------------
__global__ void k2_c(const float* __restrict__ S, const float* __restrict__ Z,
                     float* __restrict__ C) {
    int i = blockIdx.x * 256 + threadIdx.x;  // 32768
    C[i] = S[i] / Z[i >> 5];
}

// ---------------- K3: q proj + d-softmax + out = c^T q + y = Wout out + b, stats ----------------
// grid (512, 8) x 256 thr, one 64-column tile per block
__global__ __launch_bounds__(256, 3) void k3_main(const float* __restrict__ x,
                                                  const _Float16* __restrict__ Wb,
                                                  const _Float16* __restrict__ Wo,
                                                  const float* __restrict__ Cb,
                                                  const float* __restrict__ b_out,
                                                  float* __restrict__ yout,
                                                  float* __restrict__ St) {
    __shared__ _Float16 Xb[64][136];
    __shared__ _Float16 qT[64][136];  // [j][d 0..127]
    __shared__ _Float16 oT[64][136];  // [j][c 0..127]
    __shared__ float red[8];
    const int t = threadIdx.x;
    const int lane = t & 63, w = t >> 6, g = lane >> 4, l15 = lane & 15;
    const int b = blockIdx.y;
    const int j0 = blockIdx.x * 64;

    // stage x^T tile
    {
        const int j4 = t & 15, c0 = t >> 4;
#pragma unroll
        for (int cc = 0; cc < 8; ++cc) {
            const int c = c0 + 16 * cc;
            const float4 v4 = *(const float4*)(x + ((size_t)b * DIMC + c) * NTOT + j0 + 4 * j4);
            Xb[4 * j4 + 0][c] = (_Float16)v4.x;
            Xb[4 * j4 + 1][c] = (_Float16)v4.y;
            Xb[4 * j4 + 2][c] = (_Float16)v4.z;
            Xb[4 * j4 + 3][c] = (_Float16)v4.w;
        }
    }
    __syncthreads();
    // q GEMM (rows 0..127): wave w handles m-tiles 2w, 2w+1; write q^T to LDS
    {
        half8 bf[4][4];
#pragma unroll
        for (int nt = 0; nt < 4; ++nt)
#pragma unroll
            for (int kc = 0; kc < 4; ++kc)
                bf[nt][kc] = *(const half8*)(&Xb[nt * 16 + l15][kc * 32 + 8 * g]);
#pragma unroll
        for (int mi = 0; mi < 2; ++mi) {
            const int mt = w * 2 + mi;
            half8 af[4];
#pragma unroll
            for (int kc = 0; kc < 4; ++kc)
                af[kc] = *(const half8*)(Wb + (size_t)(mt * 16 + l15) * 128 + kc * 32 + 8 * g);
            f32x4 acc[4];
#pragma unroll
            for (int nt = 0; nt < 4; ++nt) acc[nt] = (f32x4){0.f, 0.f, 0.f, 0.f};
#pragma unroll
            for (int kc = 0; kc < 4; ++kc)
#pragma unroll
                for (int nt = 0; nt < 4; ++nt)
                    acc[nt] = __builtin_amdgcn_mfma_f32_16x16x32_f16(af[kc], bf[nt][kc], acc[nt], 0, 0, 0);
#pragma unroll
            for (int nt = 0; nt < 4; ++nt) {
                half4v p;
#pragma unroll
                for (int r = 0; r < 4; ++r) p[r] = (_Float16)acc[nt][r];
                *(half4v*)(&qT[nt * 16 + l15][mt * 16 + g * 4]) = p;
            }
        }
    }
    __syncthreads();
    // per-column softmax over d (32) + out = c^T q_sm  (thread = (column j, head h))
    {
        const int j = t & 63;
        const int h = __builtin_amdgcn_readfirstlane(t >> 6);  // wave-uniform -> scalar loads of c
        float qv[32];
#pragma unroll
        for (int s8 = 0; s8 < 4; ++s8) {
            half8 hv = *(const half8*)(&qT[j][h * 32 + 8 * s8]);
#pragma unroll
            for (int e = 0; e < 8; ++e) qv[8 * s8 + e] = (float)hv[e];
        }
        float se = 0.f;
#pragma unroll
        for (int d = 0; d < 32; ++d) { qv[d] = __expf(qv[d]); se += qv[d]; }
        const float inv = SCALE_Q / se;
        float outv[32];
#pragma unroll
        for (int e = 0; e < 32; ++e) outv[e] = 0.f;
        const float* ch = Cb + (size_t)(b * HEADS + h) * DHEAD * DHEAD;
#pragma unroll
        for (int d = 0; d < 32; ++d) {
            const float qd = qv[d] * inv;
#pragma unroll
            for (int e = 0; e < 32; ++e) outv[e] = fmaf(ch[d * 32 + e], qd, outv[e]);
        }
#pragma unroll
        for (int e = 0; e < 32; e += 2) {
            half2v p = {(_Float16)outv[e], (_Float16)outv[e + 1]};
            *(half2v*)(&oT[j][h * 32 + e]) = p;
        }
    }
    __syncthreads();
    // y = Wout @ out + b_out, store + stats
    float ssum = 0.f, ssq = 0.f;
    {
        half8 bf[4][4];
#pragma unroll
        for (int nt = 0; nt < 4; ++nt)
#pragma unroll
            for (int kc = 0; kc < 4; ++kc)
                bf[nt][kc] = *(const half8*)(&oT[nt * 16 + l15][kc * 32 + 8 * g]);
#pragma unroll
        for (int mi = 0; mi < 2; ++mi) {
            const int mt = w * 2 + mi;
            const int o0 = mt * 16 + g * 4;
            half8 af[4];
#pragma unroll
            for (int kc = 0; kc < 4; ++kc)
                af[kc] = *(const half8*)(Wo + (size_t)(mt * 16 + l15) * 128 + kc * 32 + 8 * g);
            f32x4 acc[4];
#pragma unroll
            for (int nt = 0; nt < 4; ++nt) acc[nt] = (f32x4){0.f, 0.f, 0.f, 0.f};
#pragma unroll
            for (int kc = 0; kc < 4; ++kc)
#pragma unroll
                for (int nt = 0; nt < 4; ++nt)
                    acc[nt] = __builtin_amdgcn_mfma_f32_16x16x32_f16(af[kc], bf[nt][kc], acc[nt], 0, 0, 0);
            float bo[4];
#pragma unroll
            for (int r = 0; r < 4; ++r) bo[r] = b_out[o0 + r];
#pragma unroll
            for (int nt = 0; nt < 4; ++nt) {
                const int jn = j0 + nt * 16 + l15;
#pragma unroll
                for (int r = 0; r < 4; ++r) {
                    const float yv = acc[nt][r] + bo[r];
                    ssum += yv;
                    ssq += yv * yv;
                    yout[((size_t)b * DIMC + o0 + r) * NTOT + jn] = yv;
                }
            }
        }
    }
#pragma unroll
    for (int m = 32; m; m >>= 1) { ssum += __shfl_xor(ssum, m); ssq += __shfl_xor(ssq, m); }
    if (lane == 0) { red[w] = ssum; red[4 + w] = ssq; }
    __syncthreads();
    if (t == 0) {
        atomicAdd(&St[b * 2 + 0], red[0] + red[1] + red[2] + red[3]);
        atomicAdd(&St[b * 2 + 1], red[4] + red[5] + red[6] + red[7]);
    }
}

// ---------------- K4: layernorm (in-place on d_out) ----------------
__global__ void k4_norm(float* __restrict__ y, const float* __restrict__ St,
                        const float* __restrict__ gamma, const float* __restrict__ beta) {
    const int o = blockIdx.x;
    const int b = blockIdx.y;
    const float n = (float)DIMC * (float)NTOT;
    const float mean = St[b * 2] / n;
    const float var = St[b * 2 + 1] / n - mean * mean;
    const float rs = rsqrtf(var + 1e-5f);
    const float ga = gamma[o] * rs;
    const float be = beta[o];
    float4* row = (float4*)(y + ((size_t)b * DIMC + o) * NTOT);
#pragma unroll 4
    for (int i = threadIdx.x; i < NTOT / 4; i += 256) {
        float4 v = row[i];
        v.x = (v.x - mean) * ga + be;
        v.y = (v.y - mean) * ga + be;
        v.z = (v.z - mean) * ga + be;
        v.w = (v.w - mean) * ga + be;
        row[i] = v;
    }
}

extern "C" void kernel_launch(void* const* d_in, const int* in_sizes, int n_in,
                              void* d_out, int out_size, void* d_ws, size_t ws_size,
                              hipStream_t stream) {
    const float* x     = (const float*)d_in[0];
    const float* wqkv  = (const float*)d_in[1];
    const float* wout  = (const float*)d_in[2];
    const float* b_out = (const float*)d_in[3];
    const float* gamma = (const float*)d_in[4];
    const float* beta  = (const float*)d_in[5];
    if (ws_size < WS_NEED) return;
    char* ws = (char*)d_ws;
    _Float16* Wb = (_Float16*)(ws + WS_WQKV);
    _Float16* Wo = (_Float16*)(ws + WS_WOUT);
    float* S  = (float*)(ws + WS_S);
    float* Z  = (float*)(ws + WS_Z);
    float* Cb = (float*)(ws + WS_C);
    float* St = (float*)(ws + WS_ST);
    float* y  = (float*)d_out;

    k0_prep<<<389, 256, 0, stream>>>(wqkv, wout, ws);
    k1_kv<<<dim3(64, 8), 256, 0, stream>>>(x, Wb, S, Z);
    k2_c<<<128, 256, 0, stream>>>(S, Z, Cb);
    k3_main<<<dim3(512, 8), 256, 0, stream>>>(x, Wb, Wo, Cb, b_out, y, St);
    k4_norm<<<dim3(128, 8), 256, 0, stream>>>(y, St, gamma, beta);
}